// Round 4
// baseline (269.938 us; speedup 1.0000x reference)
//
#include <hip/hip_runtime.h>
#include <math.h>

#define BDIM 4096
#define TDIM 2048

constexpr double gpow(int e) {
    double r = 1.0;
    for (int i = 0; i < e; ++i) r *= 0.99;
    return r;
}

__device__ __forceinline__ float logsig(float x) {
    // log(sigmoid(x)) = min(x,0) - log1p(exp(-|x|))  (matches jax.nn.log_sigmoid)
    return fminf(x, 0.0f) - log1pf(expf(-fabsf(x)));
}

// K1: one row per block. Reverse discounted scan c[t] = wr[t] + g*c[t+1].
__global__ __launch_bounds__(256) void k1_scan(
    const float* __restrict__ logits,
    const float* __restrict__ weight,
    float* __restrict__ cum_out)
{
    const int tid  = threadIdx.x;
    const int lane = tid & 63;
    const int wave = tid >> 6;
    const int t0   = tid * 8;

    const float G    = 0.99f;
    const float G8   = (float)gpow(8);
    const float G512 = (float)gpow(512);
    const float LOG2G = -0.014499569695115089f;  // log2(0.99)
    const float gk[8] = {(float)gpow(8), (float)gpow(7), (float)gpow(6), (float)gpow(5),
                         (float)gpow(4), (float)gpow(3), (float)gpow(2), (float)gpow(1)};

    __shared__ float wsum[4];

    const size_t base = (size_t)blockIdx.x * TDIM + t0;

    float4 x0 = *reinterpret_cast<const float4*>(logits + base);
    float4 x1 = *reinterpret_cast<const float4*>(logits + base + 4);
    float4 w0 = *reinterpret_cast<const float4*>(weight + base);
    float4 w1 = *reinterpret_cast<const float4*>(weight + base + 4);

    float wr[8];
    wr[0] = w0.x * logsig(x0.x); wr[1] = w0.y * logsig(x0.y);
    wr[2] = w0.z * logsig(x0.z); wr[3] = w0.w * logsig(x0.w);
    wr[4] = w1.x * logsig(x1.x); wr[5] = w1.y * logsig(x1.y);
    wr[6] = w1.z * logsig(x1.z); wr[7] = w1.w * logsig(x1.w);

    // local suffix scan within the thread's 8 elements
    float loc[8];
    loc[7] = wr[7];
#pragma unroll
    for (int k = 6; k >= 0; --k) loc[k] = fmaf(G, loc[k + 1], wr[k]);

    // wave-level weighted suffix scan over per-thread totals (factor g^8)
    float v = loc[0];
    float f = G8;
#pragma unroll
    for (int o = 1; o < 64; o <<= 1) {
        float up = __shfl_down(v, (unsigned)o, 64);
        if (lane + o < 64) v = fmaf(f, up, v);
        f *= f;
    }

    // cross-wave carry (4 waves, factor g^512)
    if (lane == 0) wsum[wave] = v;
    __syncthreads();
    const float W1 = wsum[1], W2 = wsum[2], W3 = wsum[3];
    const float FC3 = W3;
    const float FC2 = fmaf(G512, FC3, W2);
    const float FC1 = fmaf(G512, FC2, W1);
    const float carry = (wave == 0) ? FC1 : (wave == 1) ? FC2 : (wave == 2) ? FC3 : 0.0f;

    const float vfull = fmaf(exp2f((float)((64 - lane) * 8) * LOG2G), carry, v);
    const float vn = __shfl_down(vfull, 1, 64);
    const float tail = (lane == 63) ? carry : vn;

    float c[8];
#pragma unroll
    for (int k = 0; k < 8; ++k) c[k] = fmaf(gk[k], tail, loc[k]);

    *reinterpret_cast<float4*>(cum_out + base)     = make_float4(c[0], c[1], c[2], c[3]);
    *reinterpret_cast<float4*>(cum_out + base + 4) = make_float4(c[4], c[5], c[6], c[7]);
}

#define ROWS_K2 8
#define F4STRIDE (TDIM / 4)

// K2: colsum[t] = sum_b (cum[b,t] - baselines[b,t]).  grid (2, 512), 8 rows/block.
// Load-all-then-accumulate to keep all loads in flight (latency fix).
__global__ __launch_bounds__(256) void k2_colsum(
    const float* __restrict__ cum,
    const float* __restrict__ baselines,
    float* __restrict__ colsum)
{
    const int col = (blockIdx.x * 256 + threadIdx.x) * 4;
    const int r0  = blockIdx.y * ROWS_K2;
    const size_t base = (size_t)r0 * TDIM + col;
    const float4* cp = reinterpret_cast<const float4*>(cum + base);
    const float4* bp = reinterpret_cast<const float4*>(baselines + base);

    float4 c[ROWS_K2], b[ROWS_K2];
#pragma unroll
    for (int r = 0; r < ROWS_K2; ++r) c[r] = cp[(size_t)r * F4STRIDE];
#pragma unroll
    for (int r = 0; r < ROWS_K2; ++r) b[r] = bp[(size_t)r * F4STRIDE];

    float4 acc = make_float4(0.f, 0.f, 0.f, 0.f);
#pragma unroll
    for (int r = 0; r < ROWS_K2; ++r) {
        acc.x += c[r].x - b[r].x; acc.y += c[r].y - b[r].y;
        acc.z += c[r].z - b[r].z; acc.w += c[r].w - b[r].w;
    }
    atomicAdd(colsum + col,     acc.x);
    atomicAdd(colsum + col + 1, acc.y);
    atomicAdd(colsum + col + 2, acc.z);
    atomicAdd(colsum + col + 3, acc.w);
}

// K3: obj[t] = sum_b clip(cum - baseline - mean, +-5) * lp.  grid (2, 512), 8 rows/block.
__global__ __launch_bounds__(256) void k3_obj(
    const float* __restrict__ cum,
    const float* __restrict__ baselines,
    const float* __restrict__ lp,
    const float* __restrict__ colsum,
    float* __restrict__ obj)
{
    const int col = (blockIdx.x * 256 + threadIdx.x) * 4;
    const int r0  = blockIdx.y * ROWS_K2;
    const size_t base = (size_t)r0 * TDIM + col;
    const float4* cp = reinterpret_cast<const float4*>(cum + base);
    const float4* bp = reinterpret_cast<const float4*>(baselines + base);
    const float4* lpp = reinterpret_cast<const float4*>(lp + base);

    float4 m = *reinterpret_cast<const float4*>(colsum + col);
    const float inv = 1.0f / (float)BDIM;
    m.x *= inv; m.y *= inv; m.z *= inv; m.w *= inv;

    float4 c[ROWS_K2], b[ROWS_K2], l[ROWS_K2];
#pragma unroll
    for (int r = 0; r < ROWS_K2; ++r) c[r] = cp[(size_t)r * F4STRIDE];
#pragma unroll
    for (int r = 0; r < ROWS_K2; ++r) b[r] = bp[(size_t)r * F4STRIDE];
#pragma unroll
    for (int r = 0; r < ROWS_K2; ++r) l[r] = lpp[(size_t)r * F4STRIDE];

    float4 acc = make_float4(0.f, 0.f, 0.f, 0.f);
#pragma unroll
    for (int r = 0; r < ROWS_K2; ++r) {
        float ax = fminf(fmaxf(c[r].x - b[r].x - m.x, -5.0f), 5.0f);
        float ay = fminf(fmaxf(c[r].y - b[r].y - m.y, -5.0f), 5.0f);
        float az = fminf(fmaxf(c[r].z - b[r].z - m.z, -5.0f), 5.0f);
        float aw = fminf(fmaxf(c[r].w - b[r].w - m.w, -5.0f), 5.0f);
        acc.x = fmaf(ax, l[r].x, acc.x);
        acc.y = fmaf(ay, l[r].y, acc.y);
        acc.z = fmaf(az, l[r].z, acc.z);
        acc.w = fmaf(aw, l[r].w, acc.w);
    }
    atomicAdd(obj + col,     acc.x);
    atomicAdd(obj + col + 1, acc.y);
    atomicAdd(obj + col + 2, acc.z);
    atomicAdd(obj + col + 3, acc.w);
}

extern "C" void kernel_launch(void* const* d_in, const int* in_sizes, int n_in,
                              void* d_out, int out_size, void* d_ws, size_t ws_size,
                              hipStream_t stream) {
    const float* log_probs = (const float*)d_in[0];   // [B,T]
    const float* logits    = (const float*)d_in[1];   // [B,T,1]
    const float* weight    = (const float*)d_in[2];   // [B,T]
    const float* baselines = (const float*)d_in[3];   // [B,T,1]

    float* out = (float*)d_out;
    float* obj = out;            // [T]
    float* cum = out + TDIM;     // [B,T]

    float* colsum = (float*)d_ws;   // 2048 floats

    hipMemsetAsync(obj, 0, TDIM * sizeof(float), stream);
    hipMemsetAsync(colsum, 0, TDIM * sizeof(float), stream);

    k1_scan<<<BDIM, 256, 0, stream>>>(logits, weight, cum);
    k2_colsum<<<dim3(2, BDIM / ROWS_K2), 256, 0, stream>>>(cum, baselines, colsum);
    k3_obj<<<dim3(2, BDIM / ROWS_K2), 256, 0, stream>>>(cum, baselines, log_probs, colsum, obj);
}

// Round 5
// 213.888 us; speedup vs baseline: 1.2621x; 1.2621x over previous
//
#include <hip/hip_runtime.h>
#include <math.h>

#define BDIM 4096
#define TDIM 2048
#define F4STRIDE (TDIM / 4)

constexpr double gpow(int e) {
    double r = 1.0;
    for (int i = 0; i < e; ++i) r *= 0.99;
    return r;
}

__device__ __forceinline__ float logsig(float x) {
    // log(sigmoid(x)) = min(x,0) - log1p(exp(-|x|))  (matches jax.nn.log_sigmoid)
    return fminf(x, 0.0f) - log1pf(expf(-fabsf(x)));
}

// K1: one row per block. Reverse discounted scan c[t] = wr[t] + g*c[t+1].
__global__ __launch_bounds__(256) void k1_scan(
    const float* __restrict__ logits,
    const float* __restrict__ weight,
    float* __restrict__ cum_out)
{
    const int tid  = threadIdx.x;
    const int lane = tid & 63;
    const int wave = tid >> 6;
    const int t0   = tid * 8;

    const float G    = 0.99f;
    const float G8   = (float)gpow(8);
    const float G512 = (float)gpow(512);
    const float LOG2G = -0.014499569695115089f;  // log2(0.99)
    const float gk[8] = {(float)gpow(8), (float)gpow(7), (float)gpow(6), (float)gpow(5),
                         (float)gpow(4), (float)gpow(3), (float)gpow(2), (float)gpow(1)};

    __shared__ float wsum[4];

    const size_t base = (size_t)blockIdx.x * TDIM + t0;

    float4 x0 = *reinterpret_cast<const float4*>(logits + base);
    float4 x1 = *reinterpret_cast<const float4*>(logits + base + 4);
    float4 w0 = *reinterpret_cast<const float4*>(weight + base);
    float4 w1 = *reinterpret_cast<const float4*>(weight + base + 4);

    float wr[8];
    wr[0] = w0.x * logsig(x0.x); wr[1] = w0.y * logsig(x0.y);
    wr[2] = w0.z * logsig(x0.z); wr[3] = w0.w * logsig(x0.w);
    wr[4] = w1.x * logsig(x1.x); wr[5] = w1.y * logsig(x1.y);
    wr[6] = w1.z * logsig(x1.z); wr[7] = w1.w * logsig(x1.w);

    // local suffix scan within the thread's 8 elements
    float loc[8];
    loc[7] = wr[7];
#pragma unroll
    for (int k = 6; k >= 0; --k) loc[k] = fmaf(G, loc[k + 1], wr[k]);

    // wave-level weighted suffix scan over per-thread totals (factor g^8)
    float v = loc[0];
    float f = G8;
#pragma unroll
    for (int o = 1; o < 64; o <<= 1) {
        float up = __shfl_down(v, (unsigned)o, 64);
        if (lane + o < 64) v = fmaf(f, up, v);
        f *= f;
    }

    // cross-wave carry (4 waves, factor g^512)
    if (lane == 0) wsum[wave] = v;
    __syncthreads();
    const float W1 = wsum[1], W2 = wsum[2], W3 = wsum[3];
    const float FC3 = W3;
    const float FC2 = fmaf(G512, FC3, W2);
    const float FC1 = fmaf(G512, FC2, W1);
    const float carry = (wave == 0) ? FC1 : (wave == 1) ? FC2 : (wave == 2) ? FC3 : 0.0f;

    const float vfull = fmaf(exp2f((float)((64 - lane) * 8) * LOG2G), carry, v);
    const float vn = __shfl_down(vfull, 1, 64);
    const float tail = (lane == 63) ? carry : vn;

    float c[8];
#pragma unroll
    for (int k = 0; k < 8; ++k) c[k] = fmaf(gk[k], tail, loc[k]);

    *reinterpret_cast<float4*>(cum_out + base)     = make_float4(c[0], c[1], c[2], c[3]);
    *reinterpret_cast<float4*>(cum_out + base + 4) = make_float4(c[4], c[5], c[6], c[7]);
}

// K2: partial[by][t] = sum over 8 rows of (cum - baselines). grid (2, 512). NO atomics.
#define ROWS_K2 8
__global__ __launch_bounds__(256) void k2_partial(
    const float* __restrict__ cum,
    const float* __restrict__ baselines,
    float* __restrict__ partial)
{
    const int col = (blockIdx.x * 256 + threadIdx.x) * 4;
    const int r0  = blockIdx.y * ROWS_K2;
    const size_t base = (size_t)r0 * TDIM + col;
    const float4* cp = reinterpret_cast<const float4*>(cum + base);
    const float4* bp = reinterpret_cast<const float4*>(baselines + base);

    float4 c[ROWS_K2], b[ROWS_K2];
#pragma unroll
    for (int r = 0; r < ROWS_K2; ++r) c[r] = cp[(size_t)r * F4STRIDE];
#pragma unroll
    for (int r = 0; r < ROWS_K2; ++r) b[r] = bp[(size_t)r * F4STRIDE];

    float4 acc = make_float4(0.f, 0.f, 0.f, 0.f);
#pragma unroll
    for (int r = 0; r < ROWS_K2; ++r) {
        acc.x += c[r].x - b[r].x; acc.y += c[r].y - b[r].y;
        acc.z += c[r].z - b[r].z; acc.w += c[r].w - b[r].w;
    }
    *reinterpret_cast<float4*>(partial + (size_t)blockIdx.y * TDIM + col) = acc;
}

// K2b: mean[t] = (1/B) * sum_{by=0..511} partial[by][t].  8 blocks x 256 threads.
__global__ __launch_bounds__(256) void k2_mean(
    const float* __restrict__ partial, float* __restrict__ mean)
{
    const int col = blockIdx.x * 256 + threadIdx.x;
    float s = 0.0f;
    const float* p = partial + col;
#pragma unroll 8
    for (int r = 0; r < 512; ++r) s += p[(size_t)r * TDIM];
    mean[col] = s * (1.0f / (float)BDIM);
}

// K3: partial2[by][t] = sum over 16 rows of clip(cum-baseline-mean)*lp. grid (2, 256). NO atomics.
#define ROWS_K3 16
__global__ __launch_bounds__(256) void k3_partial(
    const float* __restrict__ cum,
    const float* __restrict__ baselines,
    const float* __restrict__ lp,
    const float* __restrict__ mean,
    float* __restrict__ partial2)
{
    const int col = (blockIdx.x * 256 + threadIdx.x) * 4;
    const int r0  = blockIdx.y * ROWS_K3;
    const size_t base = (size_t)r0 * TDIM + col;
    const float4* cp  = reinterpret_cast<const float4*>(cum + base);
    const float4* bp  = reinterpret_cast<const float4*>(baselines + base);
    const float4* lpp = reinterpret_cast<const float4*>(lp + base);

    const float4 m = *reinterpret_cast<const float4*>(mean + col);

    float4 acc = make_float4(0.f, 0.f, 0.f, 0.f);
#pragma unroll
    for (int h = 0; h < 2; ++h) {
        float4 c[8], b[8], l[8];
#pragma unroll
        for (int r = 0; r < 8; ++r) c[r] = cp[(size_t)(h * 8 + r) * F4STRIDE];
#pragma unroll
        for (int r = 0; r < 8; ++r) b[r] = bp[(size_t)(h * 8 + r) * F4STRIDE];
#pragma unroll
        for (int r = 0; r < 8; ++r) l[r] = lpp[(size_t)(h * 8 + r) * F4STRIDE];
#pragma unroll
        for (int r = 0; r < 8; ++r) {
            float ax = fminf(fmaxf(c[r].x - b[r].x - m.x, -5.0f), 5.0f);
            float ay = fminf(fmaxf(c[r].y - b[r].y - m.y, -5.0f), 5.0f);
            float az = fminf(fmaxf(c[r].z - b[r].z - m.z, -5.0f), 5.0f);
            float aw = fminf(fmaxf(c[r].w - b[r].w - m.w, -5.0f), 5.0f);
            acc.x = fmaf(ax, l[r].x, acc.x);
            acc.y = fmaf(ay, l[r].y, acc.y);
            acc.z = fmaf(az, l[r].z, acc.z);
            acc.w = fmaf(aw, l[r].w, acc.w);
        }
    }
    *reinterpret_cast<float4*>(partial2 + (size_t)blockIdx.y * TDIM + col) = acc;
}

// K3b: obj[t] = sum_{by=0..255} partial2[by][t].  8 blocks x 256 threads.
__global__ __launch_bounds__(256) void k3_reduce(
    const float* __restrict__ partial2, float* __restrict__ obj)
{
    const int col = blockIdx.x * 256 + threadIdx.x;
    float s = 0.0f;
    const float* p = partial2 + col;
#pragma unroll 8
    for (int r = 0; r < 256; ++r) s += p[(size_t)r * TDIM];
    obj[col] = s;
}

extern "C" void kernel_launch(void* const* d_in, const int* in_sizes, int n_in,
                              void* d_out, int out_size, void* d_ws, size_t ws_size,
                              hipStream_t stream) {
    const float* log_probs = (const float*)d_in[0];   // [B,T]
    const float* logits    = (const float*)d_in[1];   // [B,T,1]
    const float* weight    = (const float*)d_in[2];   // [B,T]
    const float* baselines = (const float*)d_in[3];   // [B,T,1]

    float* out = (float*)d_out;
    float* obj = out;            // [T]
    float* cum = out + TDIM;     // [B,T]

    // ws layout: partial [512][2048] floats (4 MB); mean [2048] floats (8 KB).
    // partial2 [256][2048] (2 MB) reuses partial's space AFTER k2_mean consumed it.
    float* partial  = (float*)d_ws;
    float* mean     = partial + (size_t)512 * TDIM;
    float* partial2 = partial;

    k1_scan<<<BDIM, 256, 0, stream>>>(logits, weight, cum);
    k2_partial<<<dim3(2, BDIM / ROWS_K2), 256, 0, stream>>>(cum, baselines, partial);
    k2_mean<<<TDIM / 256, 256, 0, stream>>>(partial, mean);
    k3_partial<<<dim3(2, BDIM / ROWS_K3), 256, 0, stream>>>(cum, baselines, log_probs, mean, partial2);
    k3_reduce<<<TDIM / 256, 256, 0, stream>>>(partial2, obj);
}